// Round 6
// baseline (664.064 us; speedup 1.0000x reference)
//
#include <hip/hip_runtime.h>
#include <hip/hip_bf16.h>

typedef __attribute__((ext_vector_type(8))) short short8;
typedef __attribute__((ext_vector_type(4))) float f32x4;

__device__ __forceinline__ float bfu2f(unsigned short u) {
    unsigned int x = ((unsigned int)u) << 16;
    float f;
    __builtin_memcpy(&f, &x, 4);
    return f;
}
__device__ __forceinline__ unsigned short f2bfu(float f) {
    unsigned int x;
    __builtin_memcpy(&x, &f, 4);
    unsigned int r = (x + 0x7FFFu + ((x >> 16) & 1u)) >> 16;
    return (unsigned short)r;
}

// async global->LDS, 16B per lane. LDS dest is wave-uniform base + lane*16.
__device__ __forceinline__ void gload_lds16(const void* g, void* l) {
    __builtin_amdgcn_global_load_lds(
        (const __attribute__((address_space(1))) void*)g,
        (__attribute__((address_space(3))) void*)l, 16, 0, 0);
}

#define BM 128
#define BN 128
#define BK 32
#define LDA 32   // linear LDS rows (global_load_lds requires no padding)
#define BCAP 64  // adjacency bucket capacity (P(deg>64) ~ 1e-20 at Poisson(16))

// ---------------- stage-1 GEMM (proven 128x128 path) ----------------
template<bool F32OUT>
__device__ __forceinline__ void gemm_tile(
    const unsigned short* __restrict__ Alo,
    const unsigned short* __restrict__ Ahi,
    const unsigned short* __restrict__ B,
    const float* __restrict__ bias,
    void* __restrict__ Cv,
    int M, int N, int K, int relu, int m0, int n0,
    unsigned short* As, unsigned short* Bs)
{
    const int tid  = threadIdx.x;
    const int lane = tid & 63;
    const int wave = tid >> 6;
    const int wr   = wave >> 1;
    const int wc   = wave & 1;
    const int fm   = lane & 15;
    const int fq   = lane >> 4;

    f32x4 acc[4][4] = {};
    const int wbase = tid & ~63;

    for (int k0 = 0; k0 < K; k0 += BK) {
        __syncthreads();
        const unsigned short* Ab = (k0 < 128) ? Alo : Ahi;
        const int ka = (k0 < 128) ? k0 : (k0 - 128);
        #pragma unroll
        for (int i = 0; i < 2; ++i) {
            int c  = i * 256 + tid;
            int r  = c >> 2;
            int c8 = (c & 3) << 3;
            int grow = m0 + r;
            if (grow >= M) grow = M - 1;
            gload_lds16(Ab + (size_t)grow * 128 + ka + c8,
                        &As[(i * 256 + wbase) * 8]);
            gload_lds16(B + (size_t)(n0 + r) * K + k0 + c8,
                        &Bs[(i * 256 + wbase) * 8]);
        }
        __syncthreads();

        short8 af[4], bf[4];
        #pragma unroll
        for (int i = 0; i < 4; ++i)
            af[i] = *(const short8*)(&As[(wr * 64 + i * 16 + fm) * LDA + fq * 8]);
        #pragma unroll
        for (int j = 0; j < 4; ++j)
            bf[j] = *(const short8*)(&Bs[(wc * 64 + j * 16 + fm) * LDA + fq * 8]);

        #pragma unroll
        for (int i = 0; i < 4; ++i)
            #pragma unroll
            for (int j = 0; j < 4; ++j)
                acc[i][j] = __builtin_amdgcn_mfma_f32_16x16x32_bf16(
                                af[i], bf[j], acc[i][j], 0, 0, 0);
    }

    #pragma unroll
    for (int i = 0; i < 4; ++i) {
        #pragma unroll
        for (int r = 0; r < 4; ++r) {
            int gm = m0 + wr * 64 + i * 16 + fq * 4 + r;
            if (gm < M) {
                #pragma unroll
                for (int j = 0; j < 4; ++j) {
                    int gn = n0 + wc * 64 + j * 16 + fm;
                    float val = acc[i][j][r];
                    if (bias) val += bias[gn];
                    if (relu) val = fmaxf(val, 0.0f);
                    if (F32OUT)
                        __builtin_nontemporal_store(val,
                            &((float*)Cv)[(size_t)gm * N + gn]);
                    else
                        ((unsigned short*)Cv)[(size_t)gm * N + gn] = f2bfu(val);
                }
            }
        }
    }
}

// Fused stage-1 GEMM + single-pass bucket adjacency build.
__global__ __launch_bounds__(256, 2)
void gemm1_fill_k(const unsigned short* __restrict__ xb,
                  const unsigned short* __restrict__ awb,
                  const float* __restrict__ bias,
                  unsigned short* __restrict__ y, int M, int MT,
                  const int* __restrict__ ei, int* __restrict__ cnt,
                  int* __restrict__ adj, int E)
{
    __shared__ unsigned short As[BM * LDA];
    __shared__ unsigned short Bs[BN * LDA];

    int b = blockIdx.x;
    if (b < MT) {
        gemm_tile<false>(xb, xb, awb, bias, y, M, 128, 128, 0, b * BM, 0, As, Bs);
        return;
    }
    int e = ((b - MT) * 256 + (int)threadIdx.x) * 4;
    if (e >= E) return;
    if (e + 3 < E) {
        int4 u = *(const int4*)(ei + e);
        int4 v = *(const int4*)(ei + E + e);
        int p0 = atomicAdd(&cnt[u.x], 1);
        int p1 = atomicAdd(&cnt[u.y], 1);
        int p2 = atomicAdd(&cnt[u.z], 1);
        int p3 = atomicAdd(&cnt[u.w], 1);
        if (p0 < BCAP) adj[((size_t)u.x << 6) + p0] = v.x;
        if (p1 < BCAP) adj[((size_t)u.y << 6) + p1] = v.y;
        if (p2 < BCAP) adj[((size_t)u.z << 6) + p2] = v.z;
        if (p3 < BCAP) adj[((size_t)u.w << 6) + p3] = v.w;
    } else {
        for (int j = 0; j < 4 && e + j < E; ++j) {
            int u = ei[e + j], v = ei[E + e + j];
            int p = atomicAdd(&cnt[u], 1);
            if (p < BCAP) adj[((size_t)u << 6) + p] = v;
        }
    }
}

// ---------------- stage-3 GEMM: 256x256 8-phase template ----------------
// C[M,N] = A[M,256] * B[N,256]^T, A = [xb | hnb] split at k=128.
// 512 thr = 8 waves (2M x 4N); BK=64 -> 4 K-tiles; 2 iterations x 8 phases.
// LDS 128 KiB: [buf][A/B][half(128 rows)][128*64 bf16], linear, XOR-swizzled
// via pre-swizzled global source (both-sides rule): 16B slot s' = s ^ (r&7).
#define BM2 256
#define BN2 256

// stage one unit (128 rows x 64 cols bf16 = 16KB): 2 gload_lds16 per thread.
__device__ __forceinline__ void stage_unit(const unsigned short* __restrict__ src,
                                           int stride, int row0, int rmax,
                                           unsigned short* dst, int tid)
{
    #pragma unroll
    for (int j = 0; j < 2; ++j) {
        int c = j * 512 + tid;
        int r = c >> 3;
        int s = (c & 7) ^ (r & 7);       // pre-swizzled 16B slot
        int grow = row0 + r;
        if (grow > rmax) grow = rmax;    // clamp: garbage only hits guarded rows
        gload_lds16(src + (size_t)grow * stride + s * 8,
                    dst + (size_t)(j * 512 + (tid & ~63)) * 8);
    }
}

// swizzled fragment read: row-local [0..127], ks in {0,1}, fq in {0..3}
__device__ __forceinline__ short8 frag_ld(const unsigned short* base, int row,
                                          int ks, int fq)
{
    int cb = (ks * 64 + fq * 16) ^ ((row & 7) << 4);   // byte col, XOR-deswizzle
    return *(const short8*)((const char*)(base + row * 64) + cb);
}

__device__ __forceinline__ void load_a4(short8 (&a)[4][2],
    const unsigned short* base, int wr, int fm, int fq)
{
    #pragma unroll
    for (int mi = 0; mi < 4; ++mi)
        #pragma unroll
        for (int ks = 0; ks < 2; ++ks)
            a[mi][ks] = frag_ld(base, wr * 64 + mi * 16 + fm, ks, fq);
}
__device__ __forceinline__ void load_b2(short8 (&bb)[2][2],
    const unsigned short* base, int wc, int fm, int fq)
{
    #pragma unroll
    for (int nj = 0; nj < 2; ++nj)
        #pragma unroll
        for (int ks = 0; ks < 2; ++ks)
            bb[nj][ks] = frag_ld(base, wc * 32 + nj * 16 + fm, ks, fq);
}

#define PH_MID() do { \
    __builtin_amdgcn_s_barrier(); \
    asm volatile("s_waitcnt lgkmcnt(0)" ::: "memory"); \
    __builtin_amdgcn_sched_barrier(0); \
    __builtin_amdgcn_s_setprio(1); \
} while (0)
#define PH_END() do { \
    __builtin_amdgcn_s_setprio(0); \
    __builtin_amdgcn_s_barrier(); \
    asm volatile("" ::: "memory"); \
} while (0)

template<int QM, int QN>
__device__ __forceinline__ void do_mfma(f32x4 (&acc)[2][4][2][2],
                                        short8 (&a)[4][2], short8 (&b)[2][2][2])
{
    #pragma unroll
    for (int mi = 0; mi < 4; ++mi)
        #pragma unroll
        for (int nj = 0; nj < 2; ++nj)
            #pragma unroll
            for (int ks = 0; ks < 2; ++ks)
                acc[QM][mi][QN][nj] = __builtin_amdgcn_mfma_f32_16x16x32_bf16(
                    a[mi][ks], b[QN][nj][ks], acc[QM][mi][QN][nj], 0, 0, 0);
}

__global__ __launch_bounds__(512, 2)
void gemm3_8ph(const unsigned short* __restrict__ xb,   // [M,128]
               const unsigned short* __restrict__ hnb,  // [M,128]
               const unsigned short* __restrict__ lwb,  // [N,256]
               float* __restrict__ out, int M, int N)
{
    __shared__ unsigned short lds[2][2][2][128 * 64];   // 128 KiB

    const int tid = threadIdx.x;
    const int nx  = gridDim.x;                      // N tiles (4)
    const int nwg = nx * gridDim.y;
    int orig = blockIdx.y * nx + blockIdx.x;
    // bijective chunked XCD swizzle (works for nwg % 8 != 0)
    int q = nwg >> 3, r8 = nwg & 7;
    int xcd = orig & 7, pos = orig >> 3;
    int wg = (xcd < r8 ? xcd * (q + 1) : r8 * (q + 1) + (xcd - r8) * q) + pos;
    const int m0 = (wg / nx) * BM2;
    const int n0 = (wg % nx) * BN2;

    const int lane = tid & 63;
    const int wave = tid >> 6;
    const int wr = wave >> 2;     // 0..1
    const int wc = wave & 3;      // 0..3
    const int fm = lane & 15;
    const int fq = lane >> 4;
    const int rmaxA = M - 1;
    const int rmaxB = N - 1;

    f32x4 acc[2][4][2][2] = {};   // [qm][mi][qn][nj]
    short8 a[4][2];               // current A-half frags
    short8 b[2][2][2];            // [half][nj][ks]

    // prologue: T0 all 4 units + T1 {A-lo, B-lo, B-hi}; A-hi(T1) staged at ph1.
    stage_unit(xb,        128, m0,        rmaxA, &lds[0][0][0][0], tid); // A-lo T0
    stage_unit(lwb,       256, n0,        rmaxB, &lds[0][1][0][0], tid); // B-lo T0
    stage_unit(lwb,       256, n0 + 128,  rmaxB, &lds[0][1][1][0], tid); // B-hi T0
    stage_unit(xb,        128, m0 + 128,  rmaxA, &lds[0][0][1][0], tid); // A-hi T0
    stage_unit(xb + 64,   128, m0,        rmaxA, &lds[1][0][0][0], tid); // A-lo T1
    stage_unit(lwb + 64,  256, n0,        rmaxB, &lds[1][1][0][0], tid); // B-lo T1
    stage_unit(lwb + 64,  256, n0 + 128,  rmaxB, &lds[1][1][1][0], tid); // B-hi T1
    asm volatile("s_waitcnt vmcnt(6)" ::: "memory");   // T0 complete; T1 in flight
    __builtin_amdgcn_s_barrier();
    asm volatile("" ::: "memory");

    #pragma unroll
    for (int it = 0; it < 2; ++it) {
        // tiles: T=2it (buf0), T'=2it+1 (buf1); stage T+2 (buf0), T+3 (buf1)
        const unsigned short* AT1 = (it == 0) ? xb + 64 : hnb + 64;  // A src of T'

        // ph1 (T,q00): read A-lo0,B-lo0; stage A-hi(T')
        load_a4(a, &lds[0][0][0][0], wr, fm, fq);
        load_b2(b[0], &lds[0][1][0][0], wc, fm, fq);
        stage_unit(AT1, 128, m0 + 128, rmaxA, &lds[1][0][1][0], tid);
        PH_MID(); do_mfma<0, 0>(acc, a, b); PH_END();

        // ph2 (T,q01): read B-hi0; stage A-lo(T+2)
        load_b2(b[1], &lds[0][1][1][0], wc, fm, fq);
        if (it == 0) stage_unit(hnb, 128, m0, rmaxA, &lds[0][0][0][0], tid);
        PH_MID(); do_mfma<0, 1>(acc, a, b); PH_END();

        // ph3 (T,q10): read A-hi0; stage B-lo(T+2)
        load_a4(a, &lds[0][0][1][0], wr, fm, fq);
        if (it == 0) stage_unit(lwb + 128, 256, n0, rmaxB, &lds[0][1][0][0], tid);
        PH_MID(); do_mfma<1, 0>(acc, a, b); PH_END();

        // ph4 (T,q11): no reads; stage B-hi(T+2); counted vmcnt
        if (it == 0) stage_unit(lwb + 128, 256, n0 + 128, rmaxB, &lds[0][1][1][0], tid);
        PH_MID(); do_mfma<1, 1>(acc, a, b);
        __builtin_amdgcn_s_setprio(0);
        if (it == 0) asm volatile("s_waitcnt vmcnt(6)" ::: "memory");
        else         asm volatile("s_waitcnt vmcnt(0)" ::: "memory");
        __builtin_amdgcn_s_barrier();
        asm volatile("" ::: "memory");

        // ph5 (T',q00): read A-lo1,B-lo1; stage A-hi(T+2)
        load_a4(a, &lds[1][0][0][0], wr, fm, fq);
        load_b2(b[0], &lds[1][1][0][0], wc, fm, fq);
        if (it == 0) stage_unit(hnb, 128, m0 + 128, rmaxA, &lds[0][0][1][0], tid);
        PH_MID(); do_mfma<0, 0>(acc, a, b); PH_END();

        // ph6 (T',q01): read B-hi1; stage A-lo(T+3)
        load_b2(b[1], &lds[1][1][1][0], wc, fm, fq);
        if (it == 0) stage_unit(hnb + 64, 128, m0, rmaxA, &lds[1][0][0][0], tid);
        PH_MID(); do_mfma<0, 1>(acc, a, b); PH_END();

        // ph7 (T',q10): read A-hi1; stage B-lo(T+3)
        load_a4(a, &lds[1][0][1][0], wr, fm, fq);
        if (it == 0) stage_unit(lwb + 192, 256, n0, rmaxB, &lds[1][1][0][0], tid);
        PH_MID(); do_mfma<1, 0>(acc, a, b); PH_END();

        // ph8 (T',q11): no reads; stage B-hi(T+3); counted vmcnt
        if (it == 0) stage_unit(lwb + 192, 256, n0 + 128, rmaxB, &lds[1][1][1][0], tid);
        PH_MID(); do_mfma<1, 1>(acc, a, b);
        __builtin_amdgcn_s_setprio(0);
        if (it == 0) asm volatile("s_waitcnt vmcnt(6)" ::: "memory");
        __builtin_amdgcn_s_barrier();
        asm volatile("" ::: "memory");
    }

    // epilogue: relu + nontemporal fp32 store
    #pragma unroll
    for (int qm = 0; qm < 2; ++qm)
        #pragma unroll
        for (int mi = 0; mi < 4; ++mi)
            #pragma unroll
            for (int rr = 0; rr < 4; ++rr) {
                int gm = m0 + qm * 128 + wr * 64 + mi * 16 + fq * 4 + rr;
                if (gm < M) {
                    #pragma unroll
                    for (int qn = 0; qn < 2; ++qn)
                        #pragma unroll
                        for (int nj = 0; nj < 2; ++nj) {
                            int gn = n0 + qn * 128 + wc * 32 + nj * 16 + fm;
                            float v = fmaxf(acc[qm][mi][qn][nj][rr], 0.0f);
                            __builtin_nontemporal_store(v,
                                &out[(size_t)gm * N + gn]);
                        }
                }
            }
}

// ---------------- prep / gather ----------------
__device__ __forceinline__ void cvt4(const float* __restrict__ src,
                                     unsigned short* __restrict__ dst, int t)
{
    float4 f = ((const float4*)src)[t];
    ushort4 o;
    o.x = f2bfu(f.x); o.y = f2bfu(f.y); o.z = f2bfu(f.z); o.w = f2bfu(f.w);
    ((ushort4*)dst)[t] = o;
}

__global__ __launch_bounds__(256)
void prep_k(const float* __restrict__ x, unsigned short* __restrict__ xb, int n4x,
            const float* __restrict__ aW, unsigned short* __restrict__ awb, int n4a,
            const float* __restrict__ lW, unsigned short* __restrict__ lwb, int n4l,
            int* __restrict__ cnt, int n4d)
{
    int t = blockIdx.x * 256 + threadIdx.x;
    if (t < n4x) { cvt4(x, xb, t); return; }
    t -= n4x;
    if (t < n4a) { cvt4(aW, awb, t); return; }
    t -= n4a;
    if (t < n4l) { cvt4(lW, lwb, t); return; }
    t -= n4l;
    if (t < n4d) ((int4*)cnt)[t] = make_int4(0, 0, 0, 0);
}

// hn[u] = max(0, max over neighbors) via packed-i16 max on raw bf16 patterns.
__global__ __launch_bounds__(256)
void gather_max_k(const int* __restrict__ cnt, const int* __restrict__ adj,
                  const unsigned short* __restrict__ y,
                  unsigned short* __restrict__ hnb, int NN)
{
    int t = blockIdx.x * 256 + threadIdx.x;
    int u = t >> 4;
    if (u >= NN) return;
    int c = (t & 15) << 3;
    const unsigned short* yc = y + c;
    int n = cnt[u];
    if (n > BCAP) n = BCAP;
    const int* bucket = adj + ((size_t)u << 6);
    short8 a0 = {0, 0, 0, 0, 0, 0, 0, 0};
    short8 a1 = {0, 0, 0, 0, 0, 0, 0, 0};
    int i = 0;
    for (; i + 3 < n; i += 4) {
        int v0 = bucket[i], v1 = bucket[i + 1], v2 = bucket[i + 2], v3 = bucket[i + 3];
        short8 y0 = *(const short8*)(yc + (size_t)v0 * 128);
        short8 y1 = *(const short8*)(yc + (size_t)v1 * 128);
        short8 y2 = *(const short8*)(yc + (size_t)v2 * 128);
        short8 y3 = *(const short8*)(yc + (size_t)v3 * 128);
        a0 = __builtin_elementwise_max(a0, y0);
        a1 = __builtin_elementwise_max(a1, y1);
        a0 = __builtin_elementwise_max(a0, y2);
        a1 = __builtin_elementwise_max(a1, y3);
    }
    for (; i < n; ++i) {
        short8 y0 = *(const short8*)(yc + (size_t)bucket[i] * 128);
        a0 = __builtin_elementwise_max(a0, y0);
    }
    a0 = __builtin_elementwise_max(a0, a1);
    *(short8*)(hnb + (size_t)u * 128 + c) = a0;
}

extern "C" void kernel_launch(void* const* d_in, const int* in_sizes, int n_in,
                              void* d_out, int out_size, void* d_ws, size_t ws_size,
                              hipStream_t stream)
{
    const float* x     = (const float*)d_in[0]; // [N,128] f32
    const int*   ei    = (const int*)d_in[1];   // [2,E] int32
    const float* agg_W = (const float*)d_in[2]; // [128,128] f32
    const float* agg_b = (const float*)d_in[3]; // [128] f32
    const float* lin_W = (const float*)d_in[4]; // [1024,256] f32
    float*       out   = (float*)d_out;         // [N,1024] f32

    const int NN = in_sizes[0] / 128;           // 100000
    const int E  = in_sizes[1] / 2;             // 1600000
    const int DI = in_sizes[4] / 256;           // 1024

    char* ws = (char*)d_ws;
    const size_t xN = (size_t)NN * 128;
    unsigned short* xb  = (unsigned short*)ws;                 // 25.6 MB
    unsigned short* y   = xb + xN;                             // 25.6 MB
    unsigned short* hnb = y + xN;                              // 25.6 MB
    unsigned short* awb = hnb + xN;                            // 32 KB
    unsigned short* lwb = awb + 128 * 128;                     // 512 KB
    char* p = (char*)(lwb + (size_t)DI * 256);
    int* cnt = (int*)p;                                        // NN ints
    int* adj = cnt + NN;                                       // NN*64 ints (25.6 MB)

    const int MT = (NN + BM - 1) / BM;
    const int FB = (E / 4 + 255) / 256;         // fill blocks

    // Fused prep: 3x fp32->bf16 cvt + cnt zeroing, one launch.
    const int n4x = (int)(xN / 4);
    const int n4a = 128 * 128 / 4;
    const int n4l = DI * 256 / 4;
    const int n4d = (NN + 3) / 4;
    {
        long long tot = (long long)n4x + n4a + n4l + n4d;
        prep_k<<<(int)((tot + 255) / 256), 256, 0, stream>>>(
            x, xb, n4x, agg_W, awb, n4a, lin_W, lwb, n4l, cnt, n4d);
    }

    // Stage 1 GEMM + bucket adjacency build, fused (independent halves).
    gemm1_fill_k<<<MT + FB, 256, 0, stream>>>(xb, awb, agg_b, y, NN, MT,
                                              ei, cnt, adj, E);

    // Stage 2: gather-max -> hnb (bf16)
    {
        long long threads = (long long)NN * 16;
        int blocks = (int)((threads + 255) / 256);
        gather_max_k<<<blocks, 256, 0, stream>>>(cnt, adj, y, hnb, NN);
    }

    // Stage 3: out = relu([x|hn] @ lin_W^T), fp32 out — 8-phase 256^2 kernel
    {
        dim3 g(DI / BN2, (NN + BM2 - 1) / BM2);
        gemm3_8ph<<<g, 512, 0, stream>>>(xb, hnb, lwb, out, NN, DI);
    }
}

// Round 7
// 651.410 us; speedup vs baseline: 1.0194x; 1.0194x over previous
//
#include <hip/hip_runtime.h>
#include <hip/hip_bf16.h>

typedef __attribute__((ext_vector_type(8))) short short8;
typedef __attribute__((ext_vector_type(4))) float f32x4;

__device__ __forceinline__ float bfu2f(unsigned short u) {
    unsigned int x = ((unsigned int)u) << 16;
    float f;
    __builtin_memcpy(&f, &x, 4);
    return f;
}
__device__ __forceinline__ unsigned short f2bfu(float f) {
    unsigned int x;
    __builtin_memcpy(&x, &f, 4);
    unsigned int r = (x + 0x7FFFu + ((x >> 16) & 1u)) >> 16;
    return (unsigned short)r;
}

// async global->LDS, 16B per lane. LDS dest is wave-uniform base + lane*16.
__device__ __forceinline__ void gload_lds16(const void* g, void* l) {
    __builtin_amdgcn_global_load_lds(
        (const __attribute__((address_space(1))) void*)g,
        (__attribute__((address_space(3))) void*)l, 16, 0, 0);
}

#define BM 128
#define BN 128
#define BK 32
#define LDA 32   // linear LDS rows (global_load_lds requires no padding)
#define BCAP 64  // adjacency bucket capacity (P(deg>64) ~ 1e-20 at Poisson(16))

// One 128x128 output tile of C = A[M,K] * B[N,K]^T (bf16 in, fp32 accum).
// A split at k=128 between Alo/Ahi (both row-stride 128). bias optional,
// relu optional. F32OUT: fp32 (nontemporal) vs bf16 output, leading dim N.
template<bool F32OUT>
__device__ __forceinline__ void gemm_tile(
    const unsigned short* __restrict__ Alo,
    const unsigned short* __restrict__ Ahi,
    const unsigned short* __restrict__ B,
    const float* __restrict__ bias,
    void* __restrict__ Cv,
    int M, int N, int K, int relu, int m0, int n0,
    unsigned short* As, unsigned short* Bs)
{
    const int tid  = threadIdx.x;
    const int lane = tid & 63;
    const int wave = tid >> 6;
    const int wr   = wave >> 1;
    const int wc   = wave & 1;
    const int fm   = lane & 15;
    const int fq   = lane >> 4;

    f32x4 acc[4][4] = {};
    const int wbase = tid & ~63;

    for (int k0 = 0; k0 < K; k0 += BK) {
        __syncthreads();
        const unsigned short* Ab = (k0 < 128) ? Alo : Ahi;
        const int ka = (k0 < 128) ? k0 : (k0 - 128);
        #pragma unroll
        for (int i = 0; i < 2; ++i) {
            int c  = i * 256 + tid;
            int r  = c >> 2;
            int c8 = (c & 3) << 3;
            int grow = m0 + r;
            if (grow >= M) grow = M - 1;
            gload_lds16(Ab + (size_t)grow * 128 + ka + c8,
                        &As[(i * 256 + wbase) * 8]);
            gload_lds16(B + (size_t)(n0 + r) * K + k0 + c8,
                        &Bs[(i * 256 + wbase) * 8]);
        }
        __syncthreads();

        short8 af[4], bf[4];
        #pragma unroll
        for (int i = 0; i < 4; ++i)
            af[i] = *(const short8*)(&As[(wr * 64 + i * 16 + fm) * LDA + fq * 8]);
        #pragma unroll
        for (int j = 0; j < 4; ++j)
            bf[j] = *(const short8*)(&Bs[(wc * 64 + j * 16 + fm) * LDA + fq * 8]);

        #pragma unroll
        for (int i = 0; i < 4; ++i)
            #pragma unroll
            for (int j = 0; j < 4; ++j)
                acc[i][j] = __builtin_amdgcn_mfma_f32_16x16x32_bf16(
                                af[i], bf[j], acc[i][j], 0, 0, 0);
    }

    #pragma unroll
    for (int i = 0; i < 4; ++i) {
        #pragma unroll
        for (int r = 0; r < 4; ++r) {
            int gm = m0 + wr * 64 + i * 16 + fq * 4 + r;
            if (gm < M) {
                #pragma unroll
                for (int j = 0; j < 4; ++j) {
                    int gn = n0 + wc * 64 + j * 16 + fm;
                    float val = acc[i][j][r];
                    if (bias) val += bias[gn];
                    if (relu) val = fmaxf(val, 0.0f);
                    if (F32OUT)
                        __builtin_nontemporal_store(val,
                            &((float*)Cv)[(size_t)gm * N + gn]);
                    else
                        ((unsigned short*)Cv)[(size_t)gm * N + gn] = f2bfu(val);
                }
            }
        }
    }
}

// General tiled GEMM (stage 3). Grid: x = N-tiles (fastest), y = M-tiles;
// chunked XCD swizzle when nwg%8==0 (the 8 n-tiles of one m-panel run
// back-to-back on one XCD -> A panel fetched once from HBM per XCD).
template<bool F32OUT>
__global__ __launch_bounds__(256, 2)
void gemm_bt(const unsigned short* __restrict__ Alo,
             const unsigned short* __restrict__ Ahi,
             const unsigned short* __restrict__ B,
             const float* __restrict__ bias,
             void* __restrict__ Cv,
             int M, int N, int K, int relu)
{
    __shared__ unsigned short As[BM * LDA];
    __shared__ unsigned short Bs[BN * LDA];

    const int nwg  = gridDim.x * gridDim.y;
    int lid = blockIdx.y * gridDim.x + blockIdx.x;
    int wg  = lid;
    if ((nwg & 7) == 0) {                 // bijective chunked XCD swizzle
        int cpx = nwg >> 3;
        wg = (lid & 7) * cpx + (lid >> 3);
    }
    const int m0 = (wg / gridDim.x) * BM;
    const int n0 = (wg % gridDim.x) * BN;
    gemm_tile<F32OUT>(Alo, Ahi, B, bias, Cv, M, N, K, relu, m0, n0, As, Bs);
}

__device__ __forceinline__ void cvt4(const float* __restrict__ src,
                                     unsigned short* __restrict__ dst, int t)
{
    float4 f = ((const float4*)src)[t];
    ushort4 o;
    o.x = f2bfu(f.x); o.y = f2bfu(f.y); o.z = f2bfu(f.z); o.w = f2bfu(f.w);
    ((ushort4*)dst)[t] = o;
}

// Fused stage-1 GEMM + single-pass bucket adjacency build + lin_W cvt.
// Blocks [0,MT): one GEMM tile of y = x @ agg_W^T + b (bf16 out).
// Blocks [MT, MT+FB): 4 edges/thread bucket scatter.
// Blocks [MT+FB, MT+FB+LB): lin_W fp32->bf16 (needed only by stage 3, so
// it hides under GEMM1/fill here instead of prep's critical path).
__global__ __launch_bounds__(256, 2)
void gemm1_fill_k(const unsigned short* __restrict__ xb,
                  const unsigned short* __restrict__ awb,
                  const float* __restrict__ bias,
                  unsigned short* __restrict__ y, int M, int MT,
                  const int* __restrict__ ei, int* __restrict__ cnt,
                  int* __restrict__ adj, int E, int FB,
                  const float* __restrict__ lW,
                  unsigned short* __restrict__ lwb, int n4l)
{
    __shared__ unsigned short As[BM * LDA];
    __shared__ unsigned short Bs[BN * LDA];

    int b = blockIdx.x;
    if (b < MT) {
        gemm_tile<false>(xb, xb, awb, bias, y, M, 128, 128, 0, b * BM, 0, As, Bs);
        return;
    }
    if (b < MT + FB) {
        int e = ((b - MT) * 256 + (int)threadIdx.x) * 4;
        if (e >= E) return;
        if (e + 3 < E) {
            int4 u = *(const int4*)(ei + e);
            int4 v = *(const int4*)(ei + E + e);
            int p0 = atomicAdd(&cnt[u.x], 1);
            int p1 = atomicAdd(&cnt[u.y], 1);
            int p2 = atomicAdd(&cnt[u.z], 1);
            int p3 = atomicAdd(&cnt[u.w], 1);
            if (p0 < BCAP) adj[((size_t)u.x << 6) + p0] = v.x;
            if (p1 < BCAP) adj[((size_t)u.y << 6) + p1] = v.y;
            if (p2 < BCAP) adj[((size_t)u.z << 6) + p2] = v.z;
            if (p3 < BCAP) adj[((size_t)u.w << 6) + p3] = v.w;
        } else {
            for (int j = 0; j < 4 && e + j < E; ++j) {
                int u = ei[e + j], v = ei[E + e + j];
                int p = atomicAdd(&cnt[u], 1);
                if (p < BCAP) adj[((size_t)u << 6) + p] = v;
            }
        }
        return;
    }
    int t = (b - MT - FB) * 256 + (int)threadIdx.x;
    if (t < n4l) cvt4(lW, lwb, t);
}

// Fused prep: cvt x / agg_W to bf16 + zero cnt. One launch.
__global__ __launch_bounds__(256)
void prep_k(const float* __restrict__ x, unsigned short* __restrict__ xb, int n4x,
            const float* __restrict__ aW, unsigned short* __restrict__ awb, int n4a,
            int* __restrict__ cnt, int n4d)
{
    int t = blockIdx.x * 256 + threadIdx.x;
    if (t < n4x) { cvt4(x, xb, t); return; }
    t -= n4x;
    if (t < n4a) { cvt4(aW, awb, t); return; }
    t -= n4a;
    if (t < n4d) ((int4*)cnt)[t] = make_int4(0, 0, 0, 0);
}

// hn[u] = max(0, max over neighbors v of y[v]) — bucket gather, no atomics.
// 16 lanes per node, 8 channels/lane (16B loads). Packed-i16 max on raw
// bf16 patterns (monotone for non-negative; negatives lose to 0-init =
// relu clamp + empty-neighborhood). 8 neighbors in flight for latency
// hiding on the random L3-resident y reads.
__global__ __launch_bounds__(256)
void gather_max_k(const int* __restrict__ cnt, const int* __restrict__ adj,
                  const unsigned short* __restrict__ y,
                  unsigned short* __restrict__ hnb, int NN)
{
    int t = blockIdx.x * 256 + threadIdx.x;
    int u = t >> 4;
    if (u >= NN) return;
    int c = (t & 15) << 3;
    const unsigned short* yc = y + c;
    int n = cnt[u];
    if (n > BCAP) n = BCAP;
    const int* bucket = adj + ((size_t)u << 6);
    short8 a0 = {0, 0, 0, 0, 0, 0, 0, 0};
    short8 a1 = {0, 0, 0, 0, 0, 0, 0, 0};
    short8 a2 = {0, 0, 0, 0, 0, 0, 0, 0};
    short8 a3 = {0, 0, 0, 0, 0, 0, 0, 0};
    int i = 0;
    for (; i + 7 < n; i += 8) {             // 8 loads in flight
        int v0 = bucket[i],     v1 = bucket[i + 1];
        int v2 = bucket[i + 2], v3 = bucket[i + 3];
        int v4 = bucket[i + 4], v5 = bucket[i + 5];
        int v6 = bucket[i + 6], v7 = bucket[i + 7];
        short8 y0 = *(const short8*)(yc + (size_t)v0 * 128);
        short8 y1 = *(const short8*)(yc + (size_t)v1 * 128);
        short8 y2 = *(const short8*)(yc + (size_t)v2 * 128);
        short8 y3 = *(const short8*)(yc + (size_t)v3 * 128);
        short8 y4 = *(const short8*)(yc + (size_t)v4 * 128);
        short8 y5 = *(const short8*)(yc + (size_t)v5 * 128);
        short8 y6 = *(const short8*)(yc + (size_t)v6 * 128);
        short8 y7 = *(const short8*)(yc + (size_t)v7 * 128);
        a0 = __builtin_elementwise_max(a0, y0);
        a1 = __builtin_elementwise_max(a1, y1);
        a2 = __builtin_elementwise_max(a2, y2);
        a3 = __builtin_elementwise_max(a3, y3);
        a0 = __builtin_elementwise_max(a0, y4);
        a1 = __builtin_elementwise_max(a1, y5);
        a2 = __builtin_elementwise_max(a2, y6);
        a3 = __builtin_elementwise_max(a3, y7);
    }
    for (; i + 3 < n; i += 4) {
        int v0 = bucket[i],     v1 = bucket[i + 1];
        int v2 = bucket[i + 2], v3 = bucket[i + 3];
        short8 y0 = *(const short8*)(yc + (size_t)v0 * 128);
        short8 y1 = *(const short8*)(yc + (size_t)v1 * 128);
        short8 y2 = *(const short8*)(yc + (size_t)v2 * 128);
        short8 y3 = *(const short8*)(yc + (size_t)v3 * 128);
        a0 = __builtin_elementwise_max(a0, y0);
        a1 = __builtin_elementwise_max(a1, y1);
        a2 = __builtin_elementwise_max(a2, y2);
        a3 = __builtin_elementwise_max(a3, y3);
    }
    for (; i < n; ++i) {
        short8 y0 = *(const short8*)(yc + (size_t)bucket[i] * 128);
        a0 = __builtin_elementwise_max(a0, y0);
    }
    a0 = __builtin_elementwise_max(a0, a1);
    a2 = __builtin_elementwise_max(a2, a3);
    a0 = __builtin_elementwise_max(a0, a2);
    *(short8*)(hnb + (size_t)u * 128 + c) = a0;
}

extern "C" void kernel_launch(void* const* d_in, const int* in_sizes, int n_in,
                              void* d_out, int out_size, void* d_ws, size_t ws_size,
                              hipStream_t stream)
{
    const float* x     = (const float*)d_in[0]; // [N,128] f32
    const int*   ei    = (const int*)d_in[1];   // [2,E] int32
    const float* agg_W = (const float*)d_in[2]; // [128,128] f32
    const float* agg_b = (const float*)d_in[3]; // [128] f32
    const float* lin_W = (const float*)d_in[4]; // [1024,256] f32
    float*       out   = (float*)d_out;         // [N,1024] f32

    const int NN = in_sizes[0] / 128;           // 100000
    const int E  = in_sizes[1] / 2;             // 1600000
    const int DI = in_sizes[4] / 256;           // 1024

    char* ws = (char*)d_ws;
    const size_t xN = (size_t)NN * 128;
    unsigned short* xb  = (unsigned short*)ws;                 // 25.6 MB
    unsigned short* y   = xb + xN;                             // 25.6 MB
    unsigned short* hnb = y + xN;                              // 25.6 MB
    unsigned short* awb = hnb + xN;                            // 32 KB
    unsigned short* lwb = awb + 128 * 128;                     // 512 KB
    char* p = (char*)(lwb + (size_t)DI * 256);
    int* cnt = (int*)p;                                        // NN ints
    int* adj = cnt + NN;                                       // NN*64 ints (25.6 MB)

    const int MT = (NN + BM - 1) / BM;
    const int FB = (E / 4 + 255) / 256;         // fill blocks
    const int n4l = DI * 256 / 4;
    const int LB = (n4l + 255) / 256;           // lin_W cvt blocks

    // Fused prep: x/agg_W cvt + cnt zeroing (lin_W cvt moved to gemm1_fill).
    const int n4x = (int)(xN / 4);
    const int n4a = 128 * 128 / 4;
    const int n4d = (NN + 3) / 4;
    {
        long long tot = (long long)n4x + n4a + n4d;
        prep_k<<<(int)((tot + 255) / 256), 256, 0, stream>>>(
            x, xb, n4x, agg_W, awb, n4a, cnt, n4d);
    }

    // Stage 1 GEMM + bucket adjacency build + lin_W cvt, fused.
    gemm1_fill_k<<<MT + FB + LB, 256, 0, stream>>>(xb, awb, agg_b, y, NN, MT,
                                                   ei, cnt, adj, E, FB,
                                                   lin_W, lwb, n4l);

    // Stage 2: gather-max -> hnb (bf16)
    {
        long long threads = (long long)NN * 16;
        int blocks = (int)((threads + 255) / 256);
        gather_max_k<<<blocks, 256, 0, stream>>>(cnt, adj, y, hnb, NN);
    }

    // Stage 3: out = relu([x|hn] @ lin_W^T), fp32 out
    gemm_bt<true><<<dim3(DI / BN, MT), 256, 0, stream>>>(xb, hnb, lwb, nullptr, out, NN, DI, 256, 1);
}